// Round 5
// baseline (322.239 us; speedup 1.0000x reference)
//
#include <hip/hip_runtime.h>
#include <stdint.h>

// PointerNetwork forward, MI355X/gfx950 — SINGLE FUSED KERNEL.
// R14: R12/R13's asm loads wrote outputs through an ARRAY PARAMETER
// (v4f w[8] = pointer decay) => caller array became addressable => SROA
// failed => outputs lived in SCRATCH by construction (VGPR 76 proves no
// 96-wide live range existed; scratch reload from L2 every iter = same
// 255 us as remat). Fix: asm outputs returned BY VALUE in structs of
// NAMED v4f members (W8/W4); dots access members statically. Volatile asm
// still forbids remat; launch_bounds(512,2) keeps the 256-VGPR budget.
// B=256, S=64, H=128.
// RNG: JAX threefry2x32 partitionable mode: bits = o0^o1 of tf(key,(0,j)).

#define BN 256
#define SN 64
#define HN 128
#define NEGV (-1.0e9f)
#define TINYF 1.17549435e-38f

// LDS layout (floats). Lifetime aliasing:
//  A [0,8192): X (P0-P1) / H (P2-P3) / P+G (P6-P8)
//  B [8192,33280): GI (P1-P2) / WhC@8192, seT@16384, U_t@24832 (P3+)
#define OFF_A   0
#define OFF_GI  8192
#define OFF_WHC 8192
#define OFF_SET 16384
#define OFF_UT  24832
#define OFF_HC  33280   // 2*128 double-buffered x/h state
#define OFF_KK  33536   // 128 (uint32 keys)
#define OFF_SV  33664   // 128 v_att
#define OFF_DY  33792   // 128 dynamic[b]
#define OFF_WD  33920   // 256 Wd
#define OFF_CV  34176   // 128 cv
#define SMEM_FLOATS 34304   // 137216 B

typedef float v4f __attribute__((ext_vector_type(4)));

struct W8 { v4f a, b, c, d, e, f, g, h; };
struct W4 { v4f a, b, c, d; };

// 8 x dwordx4 at 64B stride, one waitcnt. Volatile => no remat/sink.
// Outputs are NAMED struct members of a by-value local => SROA-safe.
__device__ __forceinline__ W8 ldg8_s64(const float* p) {
  W8 r;
  asm volatile(
      "global_load_dwordx4 %0, %8, off\n\t"
      "global_load_dwordx4 %1, %8, off offset:64\n\t"
      "global_load_dwordx4 %2, %8, off offset:128\n\t"
      "global_load_dwordx4 %3, %8, off offset:192\n\t"
      "global_load_dwordx4 %4, %8, off offset:256\n\t"
      "global_load_dwordx4 %5, %8, off offset:320\n\t"
      "global_load_dwordx4 %6, %8, off offset:384\n\t"
      "global_load_dwordx4 %7, %8, off offset:448\n\t"
      "s_waitcnt vmcnt(0)"
      : "=&v"(r.a), "=&v"(r.b), "=&v"(r.c), "=&v"(r.d),
        "=&v"(r.e), "=&v"(r.f), "=&v"(r.g), "=&v"(r.h)
      : "v"(p));
  return r;
}

// 4 x dwordx4 at 128B stride, one waitcnt.
__device__ __forceinline__ W4 ldg4_s128(const float* p) {
  W4 r;
  asm volatile(
      "global_load_dwordx4 %0, %4, off\n\t"
      "global_load_dwordx4 %1, %4, off offset:128\n\t"
      "global_load_dwordx4 %2, %4, off offset:256\n\t"
      "global_load_dwordx4 %3, %4, off offset:384\n\t"
      "s_waitcnt vmcnt(0)"
      : "=&v"(r.a), "=&v"(r.b), "=&v"(r.c), "=&v"(r.d)
      : "v"(p));
  return r;
}

// dot of 32-float weight slice (W8) with 32-float x slice (8 float4).
__device__ __forceinline__ float dot8(const W8& w, const float4* x4) {
  float a0 = 0.f, a1 = 0.f, a2 = 0.f, a3 = 0.f;
  a0 = fmaf(w.a.x, x4[0].x, a0); a1 = fmaf(w.a.y, x4[0].y, a1);
  a2 = fmaf(w.a.z, x4[0].z, a2); a3 = fmaf(w.a.w, x4[0].w, a3);
  a0 = fmaf(w.b.x, x4[1].x, a0); a1 = fmaf(w.b.y, x4[1].y, a1);
  a2 = fmaf(w.b.z, x4[1].z, a2); a3 = fmaf(w.b.w, x4[1].w, a3);
  a0 = fmaf(w.c.x, x4[2].x, a0); a1 = fmaf(w.c.y, x4[2].y, a1);
  a2 = fmaf(w.c.z, x4[2].z, a2); a3 = fmaf(w.c.w, x4[2].w, a3);
  a0 = fmaf(w.d.x, x4[3].x, a0); a1 = fmaf(w.d.y, x4[3].y, a1);
  a2 = fmaf(w.d.z, x4[3].z, a2); a3 = fmaf(w.d.w, x4[3].w, a3);
  a0 = fmaf(w.e.x, x4[4].x, a0); a1 = fmaf(w.e.y, x4[4].y, a1);
  a2 = fmaf(w.e.z, x4[4].z, a2); a3 = fmaf(w.e.w, x4[4].w, a3);
  a0 = fmaf(w.f.x, x4[5].x, a0); a1 = fmaf(w.f.y, x4[5].y, a1);
  a2 = fmaf(w.f.z, x4[5].z, a2); a3 = fmaf(w.f.w, x4[5].w, a3);
  a0 = fmaf(w.g.x, x4[6].x, a0); a1 = fmaf(w.g.y, x4[6].y, a1);
  a2 = fmaf(w.g.z, x4[6].z, a2); a3 = fmaf(w.g.w, x4[6].w, a3);
  a0 = fmaf(w.h.x, x4[7].x, a0); a1 = fmaf(w.h.y, x4[7].y, a1);
  a2 = fmaf(w.h.z, x4[7].z, a2); a3 = fmaf(w.h.w, x4[7].w, a3);
  return (a0 + a1) + (a2 + a3);
}

// two interleaved dots of 16-float weight slices with 16-float x slice.
__device__ __forceinline__ void dot4x2(const W4& w0, const W4& w1,
                                       const float4* x4, float& s0o, float& s1o) {
  float a00 = 0.f, a01 = 0.f, a10 = 0.f, a11 = 0.f;
  a00 = fmaf(w0.a.x, x4[0].x, a00); a01 = fmaf(w0.a.y, x4[0].y, a01);
  a00 = fmaf(w0.a.z, x4[0].z, a00); a01 = fmaf(w0.a.w, x4[0].w, a01);
  a10 = fmaf(w1.a.x, x4[0].x, a10); a11 = fmaf(w1.a.y, x4[0].y, a11);
  a10 = fmaf(w1.a.z, x4[0].z, a10); a11 = fmaf(w1.a.w, x4[0].w, a11);
  a00 = fmaf(w0.b.x, x4[1].x, a00); a01 = fmaf(w0.b.y, x4[1].y, a01);
  a00 = fmaf(w0.b.z, x4[1].z, a00); a01 = fmaf(w0.b.w, x4[1].w, a01);
  a10 = fmaf(w1.b.x, x4[1].x, a10); a11 = fmaf(w1.b.y, x4[1].y, a11);
  a10 = fmaf(w1.b.z, x4[1].z, a10); a11 = fmaf(w1.b.w, x4[1].w, a11);
  a00 = fmaf(w0.c.x, x4[2].x, a00); a01 = fmaf(w0.c.y, x4[2].y, a01);
  a00 = fmaf(w0.c.z, x4[2].z, a00); a01 = fmaf(w0.c.w, x4[2].w, a01);
  a10 = fmaf(w1.c.x, x4[2].x, a10); a11 = fmaf(w1.c.y, x4[2].y, a11);
  a10 = fmaf(w1.c.z, x4[2].z, a10); a11 = fmaf(w1.c.w, x4[2].w, a11);
  a00 = fmaf(w0.d.x, x4[3].x, a00); a01 = fmaf(w0.d.y, x4[3].y, a01);
  a00 = fmaf(w0.d.z, x4[3].z, a00); a01 = fmaf(w0.d.w, x4[3].w, a01);
  a10 = fmaf(w1.d.x, x4[3].x, a10); a11 = fmaf(w1.d.y, x4[3].y, a11);
  a10 = fmaf(w1.d.z, x4[3].z, a10); a11 = fmaf(w1.d.w, x4[3].w, a11);
  s0o = a00 + a01; s1o = a10 + a11;
}

__device__ __forceinline__ uint32_t rotl32(uint32_t v, int d) {
  return (v << d) | (v >> (32 - d));
}

__device__ __forceinline__ void threefry2x32(uint32_t k0, uint32_t k1,
                                             uint32_t x0, uint32_t x1,
                                             uint32_t& o0, uint32_t& o1) {
  uint32_t ks2 = k0 ^ k1 ^ 0x1BD11BDAu;
  x0 += k0; x1 += k1;
  x0 += x1; x1 = rotl32(x1, 13); x1 ^= x0;
  x0 += x1; x1 = rotl32(x1, 15); x1 ^= x0;
  x0 += x1; x1 = rotl32(x1, 26); x1 ^= x0;
  x0 += x1; x1 = rotl32(x1, 6);  x1 ^= x0;
  x0 += k1; x1 += ks2 + 1u;
  x0 += x1; x1 = rotl32(x1, 17); x1 ^= x0;
  x0 += x1; x1 = rotl32(x1, 29); x1 ^= x0;
  x0 += x1; x1 = rotl32(x1, 16); x1 ^= x0;
  x0 += x1; x1 = rotl32(x1, 24); x1 ^= x0;
  x0 += ks2; x1 += k0 + 2u;
  x0 += x1; x1 = rotl32(x1, 13); x1 ^= x0;
  x0 += x1; x1 = rotl32(x1, 15); x1 ^= x0;
  x0 += x1; x1 = rotl32(x1, 26); x1 ^= x0;
  x0 += x1; x1 = rotl32(x1, 6);  x1 ^= x0;
  x0 += k0; x1 += k1 + 3u;
  x0 += x1; x1 = rotl32(x1, 17); x1 ^= x0;
  x0 += x1; x1 = rotl32(x1, 29); x1 ^= x0;
  x0 += x1; x1 = rotl32(x1, 16); x1 ^= x0;
  x0 += x1; x1 = rotl32(x1, 24); x1 ^= x0;
  x0 += k1; x1 += ks2 + 4u;
  x0 += x1; x1 = rotl32(x1, 13); x1 ^= x0;
  x0 += x1; x1 = rotl32(x1, 15); x1 ^= x0;
  x0 += x1; x1 = rotl32(x1, 26); x1 ^= x0;
  x0 += x1; x1 = rotl32(x1, 6);  x1 ^= x0;
  x0 += ks2; x1 += k0 + 5u;
  o0 = x0; o1 = x1;
}

__device__ __forceinline__ float jax_gumbel(uint32_t k0, uint32_t k1, int j) {
  uint32_t o0, o1;
  threefry2x32(k0, k1, 0u, (uint32_t)j, o0, o1);
  uint32_t bits = o0 ^ o1;
  uint32_t ub = (bits >> 9) | 0x3F800000u;
  float u = __uint_as_float(ub) - 1.0f;
  u = fmaxf(u + TINYF, TINYF);
  return -logf(-logf(u));
}

__device__ __forceinline__ float ftanh(float x) {
  float ax = fabsf(x);
  float e = __expf(-2.0f * ax);
  float r = (1.0f - e) * __builtin_amdgcn_rcpf(1.0f + e);
  return copysignf(r, x);
}

__device__ __forceinline__ float fsig(float x) {
  return __builtin_amdgcn_rcpf(1.0f + __expf(-x));
}

// ---------------- K0: fold dyn path through W_att2 (tiny) ----------------
__global__ void k0_dyn(const float* __restrict__ W_att, const float* __restrict__ dyn_w,
                       const float* __restrict__ dyn_b, float* __restrict__ Wd,
                       float* __restrict__ cv) {
  int h = threadIdx.x;  // 128
  float w0 = 0.f, w1 = 0.f, cc = 0.f;
  for (int k = 0; k < HN; ++k) {
    float w = W_att[h * 384 + 128 + k];
    w0 = fmaf(w, dyn_w[2 * k + 0], w0);
    w1 = fmaf(w, dyn_w[2 * k + 1], w1);
    cc = fmaf(w, dyn_b[k], cc);
  }
  Wd[2 * h] = w0; Wd[2 * h + 1] = w1; cv[h] = cc;
}

// ---------------- MEGA: everything for batch b in one block ----------------
__global__ __launch_bounds__(512, 2)   // 2nd arg = MIN WAVES PER EU => VGPR budget 256
void mega(
    const float* __restrict__ SE, const float* __restrict__ dynamic,
    const float* __restrict__ in_w, const float* __restrict__ in_b,
    const float* __restrict__ w_ih, const float* __restrict__ b_ih,
    const float* __restrict__ w_hh, const float* __restrict__ b_hh,
    const float* __restrict__ W_att, const float* __restrict__ v_att,
    const float* __restrict__ Wd, const float* __restrict__ cv,
    float* __restrict__ out) {
  extern __shared__ float sm[];
  int b = blockIdx.x, t = threadIdx.x;
  float* A   = sm + OFF_A;
  float* GIl = sm + OFF_GI;
  float* WHC = sm + OFF_WHC;
  float* SET = sm + OFF_SET;
  float* UT  = sm + OFF_UT;
  float* HC  = sm + OFF_HC;
  uint32_t* KK = (uint32_t*)(sm + OFF_KK);
  float* SV  = sm + OFF_SV;
  float* DY  = sm + OFF_DY;
  float* WDs = sm + OFF_WD;
  float* CVs = sm + OFF_CV;

  // ---- staging ----
  if (t < 64) {
    uint32_t o0, o1;
    threefry2x32(0u, 42u, 0u, (uint32_t)t, o0, o1);   // fold_in(key(42), i=t)
    KK[2 * t] = o0; KK[2 * t + 1] = o1;
  }
  if (t < 128) {
    SV[t]  = v_att[t];
    DY[t]  = dynamic[b * 128 + t];
    CVs[t] = cv[t];
    HC[t]  = SE[b * 8192 + t * 64];   // x_{-1} = SE[b,:,0] into buf0
  }
  if (t < 256) WDs[t] = Wd[t];
  __syncthreads();

  // ---- P0: x-chain. 512 thr = 128 ml x 4 ks; k-slice q*16+ks*4, q<8 ----
  {
    int ml = t >> 2, ks = t & 3;
    W8 wv = ldg8_s64(in_w + ml * HN + ks * 4);
    float bib = in_b[ml];
    for (int ii = 0; ii < SN; ++ii) {
      const float* xc = HC + (ii & 1) * 128;
      float* xn = HC + ((ii + 1) & 1) * 128;
      float4 x4[8];
#pragma unroll
      for (int q = 0; q < 8; ++q)
        x4[q] = *(const float4*)(xc + q * 16 + ks * 4);
      float s = dot8(wv, x4);
      s += __shfl_xor(s, 1); s += __shfl_xor(s, 2);
      if (ks == 0) {
        float xv = s + bib;
        A[ii * 128 + ml] = xv;   // X history
        xn[ml] = xv;
      }
      __syncthreads();
    }
  }

  // ---- P1: GI = w_ih @ X + b_ih (bulk). 128 ml x 4 ks; rows ml+128j ----
  {
    int ml = t >> 2, ks = t & 3;
    W8 wv0 = ldg8_s64(w_ih + (ml)       * HN + ks * 4);
    W8 wv1 = ldg8_s64(w_ih + (ml + 128) * HN + ks * 4);
    W8 wv2 = ldg8_s64(w_ih + (ml + 256) * HN + ks * 4);
    float bi0 = b_ih[ml], bi1 = b_ih[ml + 128], bi2 = b_ih[ml + 256];
    for (int n = 0; n < SN; ++n) {
      float4 x4[8];
#pragma unroll
      for (int q = 0; q < 8; ++q)
        x4[q] = *(const float4*)(A + n * 128 + q * 16 + ks * 4);
      float s0 = dot8(wv0, x4);
      float s1 = dot8(wv1, x4);
      float s2 = dot8(wv2, x4);
      s0 += __shfl_xor(s0, 1); s0 += __shfl_xor(s0, 2);
      s1 += __shfl_xor(s1, 1); s1 += __shfl_xor(s1, 2);
      s2 += __shfl_xor(s2, 1); s2 += __shfl_xor(s2, 2);
      if (ks == 0) {
        GIl[n * 384 + ml]       = s0 + bi0;
        GIl[n * 384 + ml + 128] = s1 + bi1;
        GIl[n * 384 + ml + 256] = s2 + bi2;
      }
    }
    __syncthreads();
  }

  // ---- P2: h-chain (GRU). 128 ml x 4 ks; rows ml+128j; lane-local tail ----
  if (t < 256) HC[t] = 0.f;
  __syncthreads();
  {
    int ml = t >> 2, ks = t & 3;
    W8 wv0 = ldg8_s64(w_hh + (ml)       * HN + ks * 4);
    W8 wv1 = ldg8_s64(w_hh + (ml + 128) * HN + ks * 4);
    W8 wv2 = ldg8_s64(w_hh + (ml + 256) * HN + ks * 4);
    float bh0 = b_hh[ml], bh1 = b_hh[ml + 128], bh2 = b_hh[ml + 256];
    float hp = 0.f;  // previous h[ml] (ks==0 lanes)
    for (int ii = 0; ii < SN; ++ii) {
      const float* hcr = HC + (ii & 1) * 128;
      float* hcw = HC + ((ii + 1) & 1) * 128;
      float4 x4[8];
#pragma unroll
      for (int q = 0; q < 8; ++q)
        x4[q] = *(const float4*)(hcr + q * 16 + ks * 4);
      float s0 = dot8(wv0, x4);
      float s1 = dot8(wv1, x4);
      float s2 = dot8(wv2, x4);
      s0 += __shfl_xor(s0, 1); s0 += __shfl_xor(s0, 2);
      s1 += __shfl_xor(s1, 1); s1 += __shfl_xor(s1, 2);
      s2 += __shfl_xor(s2, 1); s2 += __shfl_xor(s2, 2);
      if (ks == 0) {
        const float* gr = GIl + ii * 384;
        float r = fsig(gr[ml] + s0 + bh0);
        float z = fsig(gr[128 + ml] + s1 + bh1);
        float nn = ftanh(gr[256 + ml] + r * (s2 + bh2));
        float hn = (1.0f - z) * nn + z * hp;
        hcw[ml] = hn;
        A[ii * 128 + ml] = hn;   // H history
        hp = hn;
      }
      __syncthreads();
    }
  }

  // ---- P3: WhC = W_att3 @ H (bulk). 64 ml x 8 ks; 2 m-rows ----
  {
    int ml = t >> 3, ks = t & 7;
    W4 w0 = ldg4_s128(W_att + (ml)      * 384 + 256 + ks * 4);
    W4 w1 = ldg4_s128(W_att + (ml + 64) * 384 + 256 + ks * 4);
    for (int n = 0; n < SN; ++n) {
      float4 x4[4];
#pragma unroll
      for (int q = 0; q < 4; ++q)
        x4[q] = *(const float4*)(A + n * 128 + q * 32 + ks * 4);
      float s0, s1;
      dot4x2(w0, w1, x4, s0, s1);
      s0 += __shfl_xor(s0, 1); s0 += __shfl_xor(s0, 2); s0 += __shfl_xor(s0, 4);
      s1 += __shfl_xor(s1, 1); s1 += __shfl_xor(s1, 2); s1 += __shfl_xor(s1, 4);
      if (ks == 0) { WHC[n * 128 + ml] = s0; WHC[n * 128 + ml + 64] = s1; }
    }
    __syncthreads();
  }

  // ---- P4: stage SE[b] transposed: SET[s][132] = SE[b][h][s] ----
  for (int p = 0; p < 16; ++p) {
    int idx = p * 512 + t;
    int h = idx >> 6, s = idx & 63;
    SET[s * 132 + h] = SE[b * 8192 + idx];
  }
  __syncthreads();

  // ---- P5: U_t[m][66] = (W_att1 @ SE^T)[s][m] + dyn-fold (transposed) ----
  {
    int ml = t >> 3, ks = t & 7;
    W4 w0 = ldg4_s128(W_att + (ml)      * 384 + ks * 4);
    W4 w1 = ldg4_s128(W_att + (ml + 64) * 384 + ks * 4);
    for (int n = 0; n < SN; ++n) {
      float4 x4[4];
#pragma unroll
      for (int q = 0; q < 4; ++q)
        x4[q] = *(const float4*)(SET + n * 132 + q * 32 + ks * 4);
      float s0, s1;
      dot4x2(w0, w1, x4, s0, s1);
      s0 += __shfl_xor(s0, 1); s0 += __shfl_xor(s0, 2); s0 += __shfl_xor(s0, 4);
      s1 += __shfl_xor(s1, 1); s1 += __shfl_xor(s1, 2); s1 += __shfl_xor(s1, 4);
      if (ks == 0) {
        float d0 = DY[n], d1 = DY[64 + n];
        UT[(ml)      * 66 + n] = s0 + WDs[2 * ml] * d0 + WDs[2 * ml + 1] * d1 + CVs[ml];
        UT[(ml + 64) * 66 + n] = s1 + WDs[2 * (ml + 64)] * d0 + WDs[2 * (ml + 64) + 1] * d1 + CVs[ml + 64];
      }
    }
    __syncthreads();
  }

  // ---- P6: scores P[i][s] -> A[0:4096). Loop-interchanged: u once/quad ----
  {
    int s = t & 63, w = t >> 6;   // wave w owns i = w*8 + j, j<8
    float acc[8];
#pragma unroll
    for (int j = 0; j < 8; ++j) acc[j] = 0.f;
    for (int h = 0; h < HN; h += 4) {
      float u0 = UT[(h + 0) * 66 + s];
      float u1 = UT[(h + 1) * 66 + s];
      float u2 = UT[(h + 2) * 66 + s];
      float u3 = UT[(h + 3) * 66 + s];
      float4 v4 = *(const float4*)(SV + h);
#pragma unroll
      for (int j = 0; j < 8; ++j) {
        float4 wh = *(const float4*)(WHC + (w * 8 + j) * 128 + h);
        float a = acc[j];
        a = fmaf(v4.x, ftanh(u0 + wh.x), a);
        a = fmaf(v4.y, ftanh(u1 + wh.y), a);
        a = fmaf(v4.z, ftanh(u2 + wh.z), a);
        a = fmaf(v4.w, ftanh(u3 + wh.w), a);
        acc[j] = a;
      }
    }
    __syncthreads();  // UT/WHC reads done; A (aliases H) now rewritable
#pragma unroll
    for (int j = 0; j < 8; ++j) A[(w * 8 + j) * 64 + s] = acc[j];
    __syncthreads();
  }

  // ---- P7: gumbels -> A[4096:8192) ----
  {
    float* G = A + 4096;
    for (int p = 0; p < 8; ++p) {
      int idx = p * 512 + t;
      int i = idx >> 6;
      G[idx] = jax_gumbel(KK[2 * i], KK[2 * i + 1], b * 64 + (idx & 63));
    }
    __syncthreads();
  }

  // ---- P8: serial sampling (wave 0) ----
  if (t < 64) {
    const float* Pl = A;
    const float* Gl = A + 4096;
    int s = t;
    bool visited = false;
    for (int i = 0; i < SN; ++i) {
      float score = Pl[i * 64 + s];
      bool allowed = (i == 0) ? (s == 0) : (!visited);
      float logit = allowed ? score : NEGV;
      float z = logit + Gl[i * 64 + s];
      float bz = z; int bi = s;
#pragma unroll
      for (int off = 32; off > 0; off >>= 1) {
        float oz = __shfl_xor(bz, off);
        int oi = __shfl_xor(bi, off);
        if (oz > bz || (oz == bz && oi < bi)) { bz = oz; bi = oi; }
      }
      int ptr = bi;
      float m = logit;
#pragma unroll
      for (int off = 32; off > 0; off >>= 1) m = fmaxf(m, __shfl_xor(m, off));
      float e = expf(logit - m);
      float sum = e;
#pragma unroll
      for (int off = 32; off > 0; off >>= 1) sum += __shfl_xor(sum, off);
      float chosen = __shfl(logit, ptr);
      float logp = (chosen - m) - logf(sum);
      if (s == ptr) visited = true;
      if (s == 0) {
        out[b * SN + i] = (float)ptr;
        out[BN * SN + b * SN + i] = logp;
      }
    }
  }
}

// ---------------- launch ----------------
extern "C" void kernel_launch(void* const* d_in, const int* in_sizes, int n_in,
                              void* d_out, int out_size, void* d_ws, size_t ws_size,
                              hipStream_t stream) {
  const float* SE    = (const float*)d_in[1];
  const float* dynam = (const float*)d_in[2];
  const float* dyn_w = (const float*)d_in[3];
  const float* dyn_b = (const float*)d_in[4];
  const float* in_w  = (const float*)d_in[5];
  const float* in_b  = (const float*)d_in[6];
  const float* w_ih  = (const float*)d_in[7];
  const float* w_hh  = (const float*)d_in[8];
  const float* b_ih2 = (const float*)d_in[9];
  const float* b_hh  = (const float*)d_in[10];
  const float* W_att = (const float*)d_in[11];
  const float* v_att = (const float*)d_in[12];
  float* out = (float*)d_out;
  float* ws = (float*)d_ws;

  float* Wd = ws;        // 256
  float* cv = ws + 256;  // 128

  // opt-in to >64KB dynamic LDS (idempotent; not a stream op, capture-safe)
  (void)hipFuncSetAttribute((const void*)mega,
                            hipFuncAttributeMaxDynamicSharedMemorySize,
                            SMEM_FLOATS * 4);

  hipLaunchKernelGGL(k0_dyn, dim3(1), dim3(128), 0, stream,
                     W_att, dyn_w, dyn_b, Wd, cv);
  hipLaunchKernelGGL(mega, dim3(BN), dim3(512), SMEM_FLOATS * 4, stream,
                     SE, dynam, in_w, in_b, w_ih, b_ih2, w_hh, b_hh,
                     W_att, v_att, Wd, cv, out);
}

// Round 6
// 317.757 us; speedup vs baseline: 1.0141x; 1.0141x over previous
//
#include <hip/hip_runtime.h>
#include <stdint.h>

// PointerNetwork forward, MI355X/gfx950 — SINGLE FUSED KERNEL.
// R15: FIVE rounds prove loop-invariant weight slices >32 floats/thread
// can never stay register-resident (remat or spill, both = L2 refetch,
// ~255 us floor). So invert stationarity for the bulk GEMMs: P1/P3/P5
// become OUTPUT-STATIONARY over k — accumulators (48/16 regs, statically
// indexed) are the loop-carried state (unspillable-in-practice: real
// computed values), weights STREAM once from global (L1-cached lines),
// X/H/SET read via wave-uniform LDS broadcast (cg uniform per wave).
// No shfl reduces in P1/P3/P5. P0/P2 byte-identical to R14 for clean
// attribution; P2 is next if this moves.
// B=256, S=64, H=128.
// RNG: JAX threefry2x32 partitionable mode: bits = o0^o1 of tf(key,(0,j)).

#define BN 256
#define SN 64
#define HN 128
#define NEGV (-1.0e9f)
#define TINYF 1.17549435e-38f

// LDS layout (floats). Lifetime aliasing:
//  A [0,8192): X (P0-P1) / H (P2-P3) / P+G (P6-P8)
//  B [8192,33280): GI (P1-P2) / WhC@8192, seT@16384, U_t@24832 (P3+)
#define OFF_A   0
#define OFF_GI  8192
#define OFF_WHC 8192
#define OFF_SET 16384
#define OFF_UT  24832
#define OFF_HC  33280   // 2*128 double-buffered x/h state
#define OFF_KK  33536   // 128 (uint32 keys)
#define OFF_SV  33664   // 128 v_att
#define OFF_DY  33792   // 128 dynamic[b]
#define OFF_WD  33920   // 256 Wd
#define OFF_CV  34176   // 128 cv
#define SMEM_FLOATS 34304   // 137216 B

typedef float v4f __attribute__((ext_vector_type(4)));

struct W8 { v4f a, b, c, d, e, f, g, h; };

// 8 x dwordx4 at 64B stride, one waitcnt. (kept for P0/P2 control)
__device__ __forceinline__ W8 ldg8_s64(const float* p) {
  W8 r;
  asm volatile(
      "global_load_dwordx4 %0, %8, off\n\t"
      "global_load_dwordx4 %1, %8, off offset:64\n\t"
      "global_load_dwordx4 %2, %8, off offset:128\n\t"
      "global_load_dwordx4 %3, %8, off offset:192\n\t"
      "global_load_dwordx4 %4, %8, off offset:256\n\t"
      "global_load_dwordx4 %5, %8, off offset:320\n\t"
      "global_load_dwordx4 %6, %8, off offset:384\n\t"
      "global_load_dwordx4 %7, %8, off offset:448\n\t"
      "s_waitcnt vmcnt(0)"
      : "=&v"(r.a), "=&v"(r.b), "=&v"(r.c), "=&v"(r.d),
        "=&v"(r.e), "=&v"(r.f), "=&v"(r.g), "=&v"(r.h)
      : "v"(p));
  return r;
}

// dot of 32-float weight slice (W8) with 32-float x slice (8 float4).
__device__ __forceinline__ float dot8(const W8& w, const float4* x4) {
  float a0 = 0.f, a1 = 0.f, a2 = 0.f, a3 = 0.f;
  a0 = fmaf(w.a.x, x4[0].x, a0); a1 = fmaf(w.a.y, x4[0].y, a1);
  a2 = fmaf(w.a.z, x4[0].z, a2); a3 = fmaf(w.a.w, x4[0].w, a3);
  a0 = fmaf(w.b.x, x4[1].x, a0); a1 = fmaf(w.b.y, x4[1].y, a1);
  a2 = fmaf(w.b.z, x4[1].z, a2); a3 = fmaf(w.b.w, x4[1].w, a3);
  a0 = fmaf(w.c.x, x4[2].x, a0); a1 = fmaf(w.c.y, x4[2].y, a1);
  a2 = fmaf(w.c.z, x4[2].z, a2); a3 = fmaf(w.c.w, x4[2].w, a3);
  a0 = fmaf(w.d.x, x4[3].x, a0); a1 = fmaf(w.d.y, x4[3].y, a1);
  a2 = fmaf(w.d.z, x4[3].z, a2); a3 = fmaf(w.d.w, x4[3].w, a3);
  a0 = fmaf(w.e.x, x4[4].x, a0); a1 = fmaf(w.e.y, x4[4].y, a1);
  a2 = fmaf(w.e.z, x4[4].z, a2); a3 = fmaf(w.e.w, x4[4].w, a3);
  a0 = fmaf(w.f.x, x4[5].x, a0); a1 = fmaf(w.f.y, x4[5].y, a1);
  a2 = fmaf(w.f.z, x4[5].z, a2); a3 = fmaf(w.f.w, x4[5].w, a3);
  a0 = fmaf(w.g.x, x4[6].x, a0); a1 = fmaf(w.g.y, x4[6].y, a1);
  a2 = fmaf(w.g.z, x4[6].z, a2); a3 = fmaf(w.g.w, x4[6].w, a3);
  a0 = fmaf(w.h.x, x4[7].x, a0); a1 = fmaf(w.h.y, x4[7].y, a1);
  a2 = fmaf(w.h.z, x4[7].z, a2); a3 = fmaf(w.h.w, x4[7].w, a3);
  return (a0 + a1) + (a2 + a3);
}

__device__ __forceinline__ uint32_t rotl32(uint32_t v, int d) {
  return (v << d) | (v >> (32 - d));
}

__device__ __forceinline__ void threefry2x32(uint32_t k0, uint32_t k1,
                                             uint32_t x0, uint32_t x1,
                                             uint32_t& o0, uint32_t& o1) {
  uint32_t ks2 = k0 ^ k1 ^ 0x1BD11BDAu;
  x0 += k0; x1 += k1;
  x0 += x1; x1 = rotl32(x1, 13); x1 ^= x0;
  x0 += x1; x1 = rotl32(x1, 15); x1 ^= x0;
  x0 += x1; x1 = rotl32(x1, 26); x1 ^= x0;
  x0 += x1; x1 = rotl32(x1, 6);  x1 ^= x0;
  x0 += k1; x1 += ks2 + 1u;
  x0 += x1; x1 = rotl32(x1, 17); x1 ^= x0;
  x0 += x1; x1 = rotl32(x1, 29); x1 ^= x0;
  x0 += x1; x1 = rotl32(x1, 16); x1 ^= x0;
  x0 += x1; x1 = rotl32(x1, 24); x1 ^= x0;
  x0 += ks2; x1 += k0 + 2u;
  x0 += x1; x1 = rotl32(x1, 13); x1 ^= x0;
  x0 += x1; x1 = rotl32(x1, 15); x1 ^= x0;
  x0 += x1; x1 = rotl32(x1, 26); x1 ^= x0;
  x0 += x1; x1 = rotl32(x1, 6);  x1 ^= x0;
  x0 += k0; x1 += k1 + 3u;
  x0 += x1; x1 = rotl32(x1, 17); x1 ^= x0;
  x0 += x1; x1 = rotl32(x1, 29); x1 ^= x0;
  x0 += x1; x1 = rotl32(x1, 16); x1 ^= x0;
  x0 += x1; x1 = rotl32(x1, 24); x1 ^= x0;
  x0 += k1; x1 += ks2 + 4u;
  x0 += x1; x1 = rotl32(x1, 13); x1 ^= x0;
  x0 += x1; x1 = rotl32(x1, 15); x1 ^= x0;
  x0 += x1; x1 = rotl32(x1, 26); x1 ^= x0;
  x0 += x1; x1 = rotl32(x1, 6);  x1 ^= x0;
  x0 += ks2; x1 += k0 + 5u;
  o0 = x0; o1 = x1;
}

__device__ __forceinline__ float jax_gumbel(uint32_t k0, uint32_t k1, int j) {
  uint32_t o0, o1;
  threefry2x32(k0, k1, 0u, (uint32_t)j, o0, o1);
  uint32_t bits = o0 ^ o1;
  uint32_t ub = (bits >> 9) | 0x3F800000u;
  float u = __uint_as_float(ub) - 1.0f;
  u = fmaxf(u + TINYF, TINYF);
  return -logf(-logf(u));
}

__device__ __forceinline__ float ftanh(float x) {
  float ax = fabsf(x);
  float e = __expf(-2.0f * ax);
  float r = (1.0f - e) * __builtin_amdgcn_rcpf(1.0f + e);
  return copysignf(r, x);
}

__device__ __forceinline__ float fsig(float x) {
  return __builtin_amdgcn_rcpf(1.0f + __expf(-x));
}

// ---------------- K0: fold dyn path through W_att2 (tiny) ----------------
__global__ void k0_dyn(const float* __restrict__ W_att, const float* __restrict__ dyn_w,
                       const float* __restrict__ dyn_b, float* __restrict__ Wd,
                       float* __restrict__ cv) {
  int h = threadIdx.x;  // 128
  float w0 = 0.f, w1 = 0.f, cc = 0.f;
  for (int k = 0; k < HN; ++k) {
    float w = W_att[h * 384 + 128 + k];
    w0 = fmaf(w, dyn_w[2 * k + 0], w0);
    w1 = fmaf(w, dyn_w[2 * k + 1], w1);
    cc = fmaf(w, dyn_b[k], cc);
  }
  Wd[2 * h] = w0; Wd[2 * h + 1] = w1; cv[h] = cc;
}

// ---------------- MEGA: everything for batch b in one block ----------------
__global__ __launch_bounds__(512)
__attribute__((amdgpu_waves_per_eu(2, 2)))
void mega(
    const float* __restrict__ SE, const float* __restrict__ dynamic,
    const float* __restrict__ in_w, const float* __restrict__ in_b,
    const float* __restrict__ w_ih, const float* __restrict__ b_ih,
    const float* __restrict__ w_hh, const float* __restrict__ b_hh,
    const float* __restrict__ W_att, const float* __restrict__ v_att,
    const float* __restrict__ Wd, const float* __restrict__ cv,
    float* __restrict__ out) {
  extern __shared__ float sm[];
  int b = blockIdx.x, t = threadIdx.x;
  float* A   = sm + OFF_A;
  float* GIl = sm + OFF_GI;
  float* WHC = sm + OFF_WHC;
  float* SET = sm + OFF_SET;
  float* UT  = sm + OFF_UT;
  float* HC  = sm + OFF_HC;
  uint32_t* KK = (uint32_t*)(sm + OFF_KK);
  float* SV  = sm + OFF_SV;
  float* DY  = sm + OFF_DY;
  float* WDs = sm + OFF_WD;
  float* CVs = sm + OFF_CV;

  // ---- staging ----
  if (t < 64) {
    uint32_t o0, o1;
    threefry2x32(0u, 42u, 0u, (uint32_t)t, o0, o1);   // fold_in(key(42), i=t)
    KK[2 * t] = o0; KK[2 * t + 1] = o1;
  }
  if (t < 128) {
    SV[t]  = v_att[t];
    DY[t]  = dynamic[b * 128 + t];
    CVs[t] = cv[t];
    HC[t]  = SE[b * 8192 + t * 64];   // x_{-1} = SE[b,:,0] into buf0
  }
  if (t < 256) WDs[t] = Wd[t];
  __syncthreads();

  // ---- P0: x-chain. 512 thr = 128 ml x 4 ks; k-slice q*16+ks*4, q<8 ----
  {
    int ml = t >> 2, ks = t & 3;
    W8 wv = ldg8_s64(in_w + ml * HN + ks * 4);
    float bib = in_b[ml];
    for (int ii = 0; ii < SN; ++ii) {
      const float* xc = HC + (ii & 1) * 128;
      float* xn = HC + ((ii + 1) & 1) * 128;
      float4 x4[8];
#pragma unroll
      for (int q = 0; q < 8; ++q)
        x4[q] = *(const float4*)(xc + q * 16 + ks * 4);
      float s = dot8(wv, x4);
      s += __shfl_xor(s, 1); s += __shfl_xor(s, 2);
      if (ks == 0) {
        float xv = s + bib;
        A[ii * 128 + ml] = xv;   // X history
        xn[ml] = xv;
      }
      __syncthreads();
    }
  }

  // ---- P1: GI = w_ih @ X + b_ih — OUTPUT-STATIONARY over k ----
  // thread (r = t&127, cg = t>>7): rows {r, r+128, r+256} x cols cg*16..+16
  {
    int r = t & 127, cg = t >> 7;
    const float* xb = A + cg * 16 * 128;
    const float* w0p = w_ih + (r)       * HN;
    const float* w1p = w_ih + (r + 128) * HN;
    const float* w2p = w_ih + (r + 256) * HN;
    float acc[3][16];
#pragma unroll
    for (int g = 0; g < 3; ++g)
#pragma unroll
      for (int i = 0; i < 16; ++i) acc[g][i] = 0.f;
#pragma unroll 1
    for (int k = 0; k < HN; k += 4) {
      float4 w0 = *(const float4*)(w0p + k);
      float4 w1 = *(const float4*)(w1p + k);
      float4 w2 = *(const float4*)(w2p + k);
#pragma unroll
      for (int i = 0; i < 16; ++i) {
        float4 xv = *(const float4*)(xb + i * 128 + k);   // wave-uniform broadcast
        acc[0][i] = fmaf(w0.x, xv.x, acc[0][i]);
        acc[0][i] = fmaf(w0.y, xv.y, acc[0][i]);
        acc[0][i] = fmaf(w0.z, xv.z, acc[0][i]);
        acc[0][i] = fmaf(w0.w, xv.w, acc[0][i]);
        acc[1][i] = fmaf(w1.x, xv.x, acc[1][i]);
        acc[1][i] = fmaf(w1.y, xv.y, acc[1][i]);
        acc[1][i] = fmaf(w1.z, xv.z, acc[1][i]);
        acc[1][i] = fmaf(w1.w, xv.w, acc[1][i]);
        acc[2][i] = fmaf(w2.x, xv.x, acc[2][i]);
        acc[2][i] = fmaf(w2.y, xv.y, acc[2][i]);
        acc[2][i] = fmaf(w2.z, xv.z, acc[2][i]);
        acc[2][i] = fmaf(w2.w, xv.w, acc[2][i]);
      }
    }
    float b0 = b_ih[r], b1 = b_ih[r + 128], b2 = b_ih[r + 256];
#pragma unroll
    for (int i = 0; i < 16; ++i) {
      int n = cg * 16 + i;
      GIl[n * 384 + r]       = acc[0][i] + b0;   // lanes r consecutive: conflict-free
      GIl[n * 384 + 128 + r] = acc[1][i] + b1;
      GIl[n * 384 + 256 + r] = acc[2][i] + b2;
    }
    __syncthreads();
  }

  // ---- P2: h-chain (GRU). 128 ml x 4 ks; rows ml+128j; lane-local tail ----
  if (t < 256) HC[t] = 0.f;
  __syncthreads();
  {
    int ml = t >> 2, ks = t & 3;
    W8 wv0 = ldg8_s64(w_hh + (ml)       * HN + ks * 4);
    W8 wv1 = ldg8_s64(w_hh + (ml + 128) * HN + ks * 4);
    W8 wv2 = ldg8_s64(w_hh + (ml + 256) * HN + ks * 4);
    float bh0 = b_hh[ml], bh1 = b_hh[ml + 128], bh2 = b_hh[ml + 256];
    float hp = 0.f;  // previous h[ml] (ks==0 lanes)
    for (int ii = 0; ii < SN; ++ii) {
      const float* hcr = HC + (ii & 1) * 128;
      float* hcw = HC + ((ii + 1) & 1) * 128;
      float4 x4[8];
#pragma unroll
      for (int q = 0; q < 8; ++q)
        x4[q] = *(const float4*)(hcr + q * 16 + ks * 4);
      float s0 = dot8(wv0, x4);
      float s1 = dot8(wv1, x4);
      float s2 = dot8(wv2, x4);
      s0 += __shfl_xor(s0, 1); s0 += __shfl_xor(s0, 2);
      s1 += __shfl_xor(s1, 1); s1 += __shfl_xor(s1, 2);
      s2 += __shfl_xor(s2, 1); s2 += __shfl_xor(s2, 2);
      if (ks == 0) {
        const float* gr = GIl + ii * 384;
        float r = fsig(gr[ml] + s0 + bh0);
        float z = fsig(gr[128 + ml] + s1 + bh1);
        float nn = ftanh(gr[256 + ml] + r * (s2 + bh2));
        float hn = (1.0f - z) * nn + z * hp;
        hcw[ml] = hn;
        A[ii * 128 + ml] = hn;   // H history
        hp = hn;
      }
      __syncthreads();
    }
  }

  // ---- P3: WhC = W_att3 @ H — OUTPUT-STATIONARY over k ----
  {
    int r = t & 127, cg = t >> 7;
    const float* xb = A + cg * 16 * 128;
    const float* wp = W_att + r * 384 + 256;
    float acc[16];
#pragma unroll
    for (int i = 0; i < 16; ++i) acc[i] = 0.f;
#pragma unroll 1
    for (int k = 0; k < HN; k += 4) {
      float4 w = *(const float4*)(wp + k);
#pragma unroll
      for (int i = 0; i < 16; ++i) {
        float4 xv = *(const float4*)(xb + i * 128 + k);   // broadcast
        acc[i] = fmaf(w.x, xv.x, acc[i]);
        acc[i] = fmaf(w.y, xv.y, acc[i]);
        acc[i] = fmaf(w.z, xv.z, acc[i]);
        acc[i] = fmaf(w.w, xv.w, acc[i]);
      }
    }
#pragma unroll
    for (int i = 0; i < 16; ++i)
      WHC[(cg * 16 + i) * 128 + r] = acc[i];   // lanes consecutive: conflict-free
    __syncthreads();
  }

  // ---- P4: stage SE[b] transposed: SET[s][132] = SE[b][h][s] ----
  for (int p = 0; p < 16; ++p) {
    int idx = p * 512 + t;
    int h = idx >> 6, s = idx & 63;
    SET[s * 132 + h] = SE[b * 8192 + idx];
  }
  __syncthreads();

  // ---- P5: U_t = W_att1 @ SE^T + dyn-fold — OUTPUT-STATIONARY over k ----
  {
    int r = t & 127, cg = t >> 7;
    const float* xb = SET + cg * 16 * 132;
    const float* wp = W_att + r * 384;
    float acc[16];
#pragma unroll
    for (int i = 0; i < 16; ++i) acc[i] = 0.f;
#pragma unroll 1
    for (int k = 0; k < HN; k += 4) {
      float4 w = *(const float4*)(wp + k);
#pragma unroll
      for (int i = 0; i < 16; ++i) {
        float4 xv = *(const float4*)(xb + i * 132 + k);   // broadcast
        acc[i] = fmaf(w.x, xv.x, acc[i]);
        acc[i] = fmaf(w.y, xv.y, acc[i]);
        acc[i] = fmaf(w.z, xv.z, acc[i]);
        acc[i] = fmaf(w.w, xv.w, acc[i]);
      }
    }
    float wd0 = WDs[2 * r], wd1 = WDs[2 * r + 1], cvv = CVs[r];
#pragma unroll
    for (int i = 0; i < 16; ++i) {
      int n = cg * 16 + i;
      UT[r * 66 + n] = acc[i] + wd0 * DY[n] + wd1 * DY[64 + n] + cvv;
    }
    __syncthreads();
  }

  // ---- P6: scores P[i][s] -> A[0:4096). Loop-interchanged: u once/quad ----
  {
    int s = t & 63, w = t >> 6;   // wave w owns i = w*8 + j, j<8
    float acc[8];
#pragma unroll
    for (int j = 0; j < 8; ++j) acc[j] = 0.f;
    for (int h = 0; h < HN; h += 4) {
      float u0 = UT[(h + 0) * 66 + s];
      float u1 = UT[(h + 1) * 66 + s];
      float u2 = UT[(h + 2) * 66 + s];
      float u3 = UT[(h + 3) * 66 + s];
      float4 v4 = *(const float4*)(SV + h);
#pragma unroll
      for (int j = 0; j < 8; ++j) {
        float4 wh = *(const float4*)(WHC + (w * 8 + j) * 128 + h);
        float a = acc[j];
        a = fmaf(v4.x, ftanh(u0 + wh.x), a);
        a = fmaf(v4.y, ftanh(u1 + wh.y), a);
        a = fmaf(v4.z, ftanh(u2 + wh.z), a);
        a = fmaf(v4.w, ftanh(u3 + wh.w), a);
        acc[j] = a;
      }
    }
    __syncthreads();  // UT/WHC reads done; A (aliases H) now rewritable
#pragma unroll
    for (int j = 0; j < 8; ++j) A[(w * 8 + j) * 64 + s] = acc[j];
    __syncthreads();
  }

  // ---- P7: gumbels -> A[4096:8192) ----
  {
    float* G = A + 4096;
    for (int p = 0; p < 8; ++p) {
      int idx = p * 512 + t;
      int i = idx >> 6;
      G[idx] = jax_gumbel(KK[2 * i], KK[2 * i + 1], b * 64 + (idx & 63));
    }
    __syncthreads();
  }

  // ---- P8: serial sampling (wave 0) ----
  if (t < 64) {
    const float* Pl = A;
    const float* Gl = A + 4096;
    int s = t;
    bool visited = false;
    for (int i = 0; i < SN; ++i) {
      float score = Pl[i * 64 + s];
      bool allowed = (i == 0) ? (s == 0) : (!visited);
      float logit = allowed ? score : NEGV;
      float z = logit + Gl[i * 64 + s];
      float bz = z; int bi = s;
#pragma unroll
      for (int off = 32; off > 0; off >>= 1) {
        float oz = __shfl_xor(bz, off);
        int oi = __shfl_xor(bi, off);
        if (oz > bz || (oz == bz && oi < bi)) { bz = oz; bi = oi; }
      }
      int ptr = bi;
      float m = logit;
#pragma unroll
      for (int off = 32; off > 0; off >>= 1) m = fmaxf(m, __shfl_xor(m, off));
      float e = expf(logit - m);
      float sum = e;
#pragma unroll
      for (int off = 32; off > 0; off >>= 1) sum += __shfl_xor(sum, off);
      float chosen = __shfl(logit, ptr);
      float logp = (chosen - m) - logf(sum);
      if (s == ptr) visited = true;
      if (s == 0) {
        out[b * SN + i] = (float)ptr;
        out[BN * SN + b * SN + i] = logp;
      }
    }
  }
}

// ---------------- launch ----------------
extern "C" void kernel_launch(void* const* d_in, const int* in_sizes, int n_in,
                              void* d_out, int out_size, void* d_ws, size_t ws_size,
                              hipStream_t stream) {
  const float* SE    = (const float*)d_in[1];
  const float* dynam = (const float*)d_in[2];
  const float* dyn_w = (const float*)d_in[3];
  const float* dyn_b = (const float*)d_in[4];
  const float* in_w  = (const float*)d_in[5];
  const float* in_b  = (const float*)d_in[6];
  const float* w_ih  = (const float*)d_in[7];
  const float* w_hh  = (const float*)d_in[8];
  const float* b_ih2 = (const float*)d_in[9];
  const float* b_hh  = (const float*)d_in[10];
  const float* W_att = (const float*)d_in[11];
  const float* v_att = (const float*)d_in[12];
  float* out = (float*)d_out;
  float* ws = (float*)d_ws;

  float* Wd = ws;        // 256
  float* cv = ws + 256;  // 128

  // opt-in to >64KB dynamic LDS (idempotent; not a stream op, capture-safe)
  (void)hipFuncSetAttribute((const void*)mega,
                            hipFuncAttributeMaxDynamicSharedMemorySize,
                            SMEM_FLOATS * 4);

  hipLaunchKernelGGL(k0_dyn, dim3(1), dim3(128), 0, stream,
                     W_att, dyn_w, dyn_b, Wd, cv);
  hipLaunchKernelGGL(mega, dim3(BN), dim3(512), SMEM_FLOATS * 4, stream,
                     SE, dynam, in_w, in_b, w_ih, b_ih2, w_hh, b_hh,
                     W_att, v_att, Wd, cv, out);
}